// Round 11
// baseline (118.802 us; speedup 1.0000x reference)
//
#include <hip/hip_runtime.h>
#include <hip/hip_bf16.h>

// Conv2d 3x3 s1 p1, NCHW/OIHW fp32 -> fp32. bf16 implicit GEMM.
// R10: weights L2->VGPR (2-deep reg dbuf, no LDS); LDS = 12-slot input row
// ring (48KB); ONE barrier/phase; counted vmcnt; koh-pairs share XCD L2.

#define C_IN   128
#define K_OUT  256
#define HW     56
#define IMG    3136
#define NBATCH 32
#define PW     58
#define IN_WS_USHORT ((size_t)4*NBATCH*PW*256*8)     // [cq][n][py][256ch][8]
#define WT_WS_USHORT ((size_t)12*2*1536*8)           // [p][koh][1536ch][8]

typedef __bf16 bf16x8 __attribute__((ext_vector_type(8)));
typedef float  f32x4  __attribute__((ext_vector_type(4)));
typedef unsigned short ushort8 __attribute__((ext_vector_type(8)));

__device__ inline unsigned short f2bf(float f) {
    unsigned int u = __builtin_bit_cast(unsigned int, f);
    u += ((u >> 16) & 1u) + 0x7FFFu;   // RNE
    return (unsigned short)(u >> 16);
}

__device__ __forceinline__ void gl2lds16(const unsigned short* g, unsigned short* l) {
    __builtin_amdgcn_global_load_lds(
        (const __attribute__((address_space(1))) unsigned int*)g,
        (__attribute__((address_space(3))) unsigned int*)l, 16, 0, 0);
}

// ---- prep A: NCHW fp32 -> [cq][n][py][Xq:4][cc:4][Xr:16][8c] bf16 ----
__global__ void prep_input(const float* __restrict__ inp,
                           unsigned short* __restrict__ dst) {
    __shared__ unsigned short tile[C_IN * 57];   // [c][x], stride 57
    int n = blockIdx.x / PW, py = blockIdx.x % PW;
    ushort8* d8 = (ushort8*)dst;
    const bool border = (py == 0 || py == PW - 1);
    if (!border) {
        const float* src = inp + (size_t)n * C_IN * IMG + (py - 1) * HW;
        for (int i = threadIdx.x; i < C_IN * HW; i += 256) {
            int c = i / HW, x = i - c * HW;      // coalesced read along x
            tile[c * 57 + x] = f2bf(src[c * IMG + x]);
        }
        __syncthreads();
    }
    for (int i = threadIdx.x; i < 1024; i += 256) {     // 4 cq x 256 chunks
        int cq = i >> 8, rem = i & 255;
        int X = ((rem >> 6) & 3) * 16 + (rem & 15);
        int cc = (rem >> 4) & 3;
        ushort8 v = (ushort8)0;
        if (!border && X >= 1 && X <= HW) {
#pragma unroll
            for (int e = 0; e < 8; ++e)
                v[e] = tile[(cq * 32 + cc * 8 + e) * 57 + (X - 1)];
        }
        d8[((size_t)(cq * NBATCH + n) * PW + py) * 256 + rem] = v;
    }
}

// ---- prep B: OIHW fp32 -> [p=cq*3+r][koh:2][s:3][koq:8][cc:4][kor:16][8c] ----
__global__ void prep_weights(const float* __restrict__ w,
                             unsigned short* __restrict__ dst) {
    int chunk = blockIdx.x * 256 + threadIdx.x;  // 36864 chunks
    int p = chunk / 3072, rem = chunk - p * 3072;
    int koh = rem / 1536, rem2 = rem - koh * 1536;
    int s = rem2 / 512, rem3 = rem2 - s * 512;
    int koq = rem3 >> 6, cc = (rem3 >> 4) & 3, kor = rem3 & 15;
    int ko = koh * 128 + koq * 16 + kor;
    int cq = p / 3, r = p - 3 * cq;
    ushort8 v;
#pragma unroll
    for (int e = 0; e < 8; ++e)
        v[e] = f2bf(w[(ko * C_IN + cq * 32 + cc * 8 + e) * 9 + r * 3 + s]);
    ((ushort8*)dst)[chunk] = v;
}

// ---- main conv ----
// LDS: 12-slot input row ring, 4KB/slot, slot(c,t) = (6c+t) % 12.
// Weights: per-wave A fragments straight from L2 into wbuf[2][12].
__global__ __launch_bounds__(256, 2) void conv_mfma(
        const unsigned short* __restrict__ In,
        const unsigned short* __restrict__ Wt,
        const float* __restrict__ bias,
        float* __restrict__ out) {
    __shared__ unsigned short smem[24576];       // 48 KB ring

    const int tid = threadIdx.x;
    const int lane = tid & 63, wv = tid >> 6;
    const int l15 = lane & 15, lk = lane >> 4;
    const int koh = blockIdx.y;
    const int by = blockIdx.x;
    const int n = by / 14, rb = (by % 14) * 4;

    const int wkol = (wv & 1) * 64;                // wave ko base (in block)
    const int wpx  = (wv >> 1) * 112;              // wave px base (local)
    const int wlane = (wv & 1) * 2048 + lk * 128 + l15 * 8;   // W ushort off

    int yl[7], xp[3][7];
#pragma unroll
    for (int nf = 0; nf < 7; ++nf) {
        int p = wpx + nf * 16 + l15;               // local pixel 0..223
        yl[nf] = p / 56;
        int x = p - yl[nf] * 56;
#pragma unroll
        for (int s = 0; s < 3; ++s) {
            int X = x + s;
            xp[s][nf] = ((X >> 4) << 10) + lk * 256 + ((X & 15) << 4);
        }
    }

    f32x4 acc[4][7];
#pragma unroll
    for (int m = 0; m < 4; ++m)
#pragma unroll
        for (int nf = 0; nf < 7; ++nf) acc[m][nf] = (f32x4)0.0f;

    bf16x8 wbuf[2][12];

#define LOAD_W(PANEL) do {                                                  \
    const unsigned short* wp = Wt + ((size_t)((PANEL) * 2 + koh)) * 12288 + wlane; \
    _Pragma("unroll")                                                       \
    for (int s = 0; s < 3; ++s)                                             \
        _Pragma("unroll")                                                   \
        for (int m = 0; m < 4; ++m)                                         \
            wbuf[(PANEL) & 1][s * 4 + m] =                                  \
                *(const bf16x8*)(wp + s * 4096 + m * 512);                  \
} while (0)

#define STAGE_ROW(C_, T_) do {                                              \
    gl2lds16(In + ((size_t)(((C_) * NBATCH + n) * PW + rb + (T_))) * 2048 + tid * 8, \
             &smem[((6 * (C_) + (T_)) % 12) * 2048 + tid * 8]);             \
} while (0)

    // prologue: W panel 0 + input rows (0, t0..3)
    LOAD_W(0);
    STAGE_ROW(0, 0); STAGE_ROW(0, 1); STAGE_ROW(0, 2); STAGE_ROW(0, 3);

#define PHASE(PH) do {                                                      \
    constexpr int cq_ = (PH) / 3, r_ = (PH) % 3;                            \
    if constexpr ((PH) < 11) LOAD_W((PH) + 1);                              \
    if constexpr (r_ == 0) {                                                \
        STAGE_ROW(cq_, 4);                                                  \
        if constexpr (cq_ < 3) STAGE_ROW(cq_ + 1, 0);                       \
    } else if constexpr (r_ == 1) {                                         \
        STAGE_ROW(cq_, 5);                                                  \
        if constexpr (cq_ < 3) STAGE_ROW(cq_ + 1, 1);                       \
    } else {                                                                \
        if constexpr (cq_ < 3) { STAGE_ROW(cq_ + 1, 2); STAGE_ROW(cq_ + 1, 3); } \
    }                                                                       \
    { constexpr int nI = (cq_ < 3) ? 2 : (r_ == 2 ? 0 : 1);                 \
      constexpr int nW = ((PH) < 11) ? 12 : 0;                              \
      asm volatile("s_waitcnt vmcnt(%0)" :: "i"(nW + nI) : "memory"); }     \
    asm volatile("s_barrier" ::: "memory");                                 \
    { const char* ib = (const char*)smem;                                   \
      int roff[7];                                                          \
      _Pragma("unroll")                                                     \
      for (int nf = 0; nf < 7; ++nf) {                                      \
          int t = 6 * cq_ + r_ + yl[nf];                                    \
          roff[nf] = (t >= 12 ? t - 12 : t) << 12;                          \
      }                                                                     \
      __builtin_amdgcn_s_setprio(1);                                        \
      _Pragma("unroll")                                                     \
      for (int s = 0; s < 3; ++s) {                                         \
          bf16x8 b[7];                                                      \
          _Pragma("unroll")                                                 \
          for (int nf = 0; nf < 7; ++nf)                                    \
              b[nf] = *(const bf16x8*)(ib + roff[nf] + xp[s][nf]);          \
          _Pragma("unroll")                                                 \
          for (int m = 0; m < 4; ++m)                                       \
              _Pragma("unroll")                                             \
              for (int nf = 0; nf < 7; ++nf)                                \
                  acc[m][nf] = __builtin_amdgcn_mfma_f32_16x16x32_bf16(     \
                      wbuf[(PH) & 1][s * 4 + m], b[nf], acc[m][nf], 0, 0, 0); \
      }                                                                     \
      __builtin_amdgcn_s_setprio(0);                                        \
    }                                                                       \
} while (0)

    PHASE(0);  PHASE(1);  PHASE(2);  PHASE(3);
    PHASE(4);  PHASE(5);  PHASE(6);  PHASE(7);
    PHASE(8);  PHASE(9);  PHASE(10); PHASE(11);

#undef PHASE
#undef STAGE_ROW
#undef LOAD_W

    // epilogue: D col = l15 (pixel), row = lk*4 + j (ko)
    const int sp0 = rb * 56 + wpx;
#pragma unroll
    for (int m = 0; m < 4; ++m) {
        int kb = koh * 128 + wkol + m * 16 + lk * 4;
        f32x4 bs = *(const f32x4*)(bias + kb);
#pragma unroll
        for (int nf = 0; nf < 7; ++nf) {
            float* ob = out + ((size_t)(n * K_OUT + kb) * IMG) + sp0 + nf * 16 + l15;
#pragma unroll
            for (int j = 0; j < 4; ++j)
                ob[(size_t)j * IMG] = acc[m][nf][j] + bs[j];
        }
    }
}

// ---- fallback (only if ws too small): naive fp32 direct conv ----
__global__ void conv_naive(const float* __restrict__ inp,
                           const float* __restrict__ ker,
                           const float* __restrict__ bias,
                           float* __restrict__ out, int total) {
    int o = blockIdx.x * blockDim.x + threadIdx.x;
    if (o >= total) return;
    int x = o % HW, y = (o / HW) % HW, ko = (o / IMG) % K_OUT, n = o / (IMG * K_OUT);
    float acc = bias[ko];
    for (int c = 0; c < C_IN; ++c)
        for (int r = 0; r < 3; ++r) {
            int iy = y + r - 1; if ((unsigned)iy >= HW) continue;
            for (int s = 0; s < 3; ++s) {
                int ix = x + s - 1; if ((unsigned)ix >= HW) continue;
                acc += inp[((n * C_IN + c) * HW + iy) * HW + ix]
                     * ker[((ko * C_IN + c) * 3 + r) * 3 + s];
            }
        }
    out[o] = acc;
}

extern "C" void kernel_launch(void* const* d_in, const int* in_sizes, int n_in,
                              void* d_out, int out_size, void* d_ws, size_t ws_size,
                              hipStream_t stream) {
    const float* inp  = (const float*)d_in[0];
    const float* ker  = (const float*)d_in[1];
    const float* bias = (const float*)d_in[2];
    float* out = (float*)d_out;

    const size_t need = (IN_WS_USHORT + WT_WS_USHORT) * 2;
    if (ws_size < need) {
        int total = NBATCH * K_OUT * IMG;
        conv_naive<<<(total + 255) / 256, 256, 0, stream>>>(inp, ker, bias, out, total);
        return;
    }

    unsigned short* inb = (unsigned short*)d_ws;
    unsigned short* wtb = inb + IN_WS_USHORT;

    prep_input<<<NBATCH * PW, 256, 0, stream>>>(inp, inb);
    prep_weights<<<144, 256, 0, stream>>>(ker, wtb);

    conv_mfma<<<dim3(448, 2), 256, 0, stream>>>(inb, wtb, bias, out);
}

// Round 12
// 79.100 us; speedup vs baseline: 1.5019x; 1.5019x over previous
//
#include <hip/hip_runtime.h>
#include <hip/hip_bf16.h>

// Conv2d 3x3 s1 p1, NCHW/OIHW fp32 -> fp32. bf16 implicit GEMM.
// R11: weights L2->VGPR with s-slice-granular 2-deep prefetch (wbuf[2][4],
// 32 regs — fixes R10's spill). LDS = 12-slot input row ring (48KB),
// one barrier/phase, counted vmcnt for the input ring only.

#define C_IN   128
#define K_OUT  256
#define HW     56
#define IMG    3136
#define NBATCH 32
#define PW     58
#define IN_WS_USHORT ((size_t)4*NBATCH*PW*256*8)     // [cq][n][py][256ch][8]
#define WT_WS_USHORT ((size_t)12*2*1536*8)           // [p][koh][1536ch][8]

typedef __bf16 bf16x8 __attribute__((ext_vector_type(8)));
typedef float  f32x4  __attribute__((ext_vector_type(4)));
typedef unsigned short ushort8 __attribute__((ext_vector_type(8)));

__device__ inline unsigned short f2bf(float f) {
    unsigned int u = __builtin_bit_cast(unsigned int, f);
    u += ((u >> 16) & 1u) + 0x7FFFu;   // RNE
    return (unsigned short)(u >> 16);
}

__device__ __forceinline__ void gl2lds16(const unsigned short* g, unsigned short* l) {
    __builtin_amdgcn_global_load_lds(
        (const __attribute__((address_space(1))) unsigned int*)g,
        (__attribute__((address_space(3))) unsigned int*)l, 16, 0, 0);
}

// ---- prep A: NCHW fp32 -> [cq][n][py][Xq:4][cc:4][Xr:16][8c] bf16 ----
__global__ void prep_input(const float* __restrict__ inp,
                           unsigned short* __restrict__ dst) {
    __shared__ unsigned short tile[C_IN * 57];   // [c][x], stride 57
    int n = blockIdx.x / PW, py = blockIdx.x % PW;
    ushort8* d8 = (ushort8*)dst;
    const bool border = (py == 0 || py == PW - 1);
    if (!border) {
        const float* src = inp + (size_t)n * C_IN * IMG + (py - 1) * HW;
        for (int i = threadIdx.x; i < C_IN * HW; i += 256) {
            int c = i / HW, x = i - c * HW;      // coalesced read along x
            tile[c * 57 + x] = f2bf(src[c * IMG + x]);
        }
        __syncthreads();
    }
    for (int i = threadIdx.x; i < 1024; i += 256) {     // 4 cq x 256 chunks
        int cq = i >> 8, rem = i & 255;
        int X = ((rem >> 6) & 3) * 16 + (rem & 15);
        int cc = (rem >> 4) & 3;
        ushort8 v = (ushort8)0;
        if (!border && X >= 1 && X <= HW) {
#pragma unroll
            for (int e = 0; e < 8; ++e)
                v[e] = tile[(cq * 32 + cc * 8 + e) * 57 + (X - 1)];
        }
        d8[((size_t)(cq * NBATCH + n) * PW + py) * 256 + rem] = v;
    }
}

// ---- prep B: OIHW fp32 -> [p=cq*3+r][koh:2][s:3][koq:8][cc:4][kor:16][8c] ----
__global__ void prep_weights(const float* __restrict__ w,
                             unsigned short* __restrict__ dst) {
    int chunk = blockIdx.x * 256 + threadIdx.x;  // 36864 chunks
    int p = chunk / 3072, rem = chunk - p * 3072;
    int koh = rem / 1536, rem2 = rem - koh * 1536;
    int s = rem2 / 512, rem3 = rem2 - s * 512;
    int koq = rem3 >> 6, cc = (rem3 >> 4) & 3, kor = rem3 & 15;
    int ko = koh * 128 + koq * 16 + kor;
    int cq = p / 3, r = p - 3 * cq;
    ushort8 v;
#pragma unroll
    for (int e = 0; e < 8; ++e)
        v[e] = f2bf(w[(ko * C_IN + cq * 32 + cc * 8 + e) * 9 + r * 3 + s]);
    ((ushort8*)dst)[chunk] = v;
}

// ---- main conv ----
// LDS: 12-slot input row ring, 4KB/slot, slot(c,t) = (6c+t) % 12.
// Weights: per-wave A s-slices straight from L2 into wbuf[2][4] (2-deep).
__global__ __launch_bounds__(256, 2) void conv_mfma(
        const unsigned short* __restrict__ In,
        const unsigned short* __restrict__ Wt,
        const float* __restrict__ bias,
        float* __restrict__ out) {
    __shared__ unsigned short smem[24576];       // 48 KB ring

    const int tid = threadIdx.x;
    const int lane = tid & 63, wv = tid >> 6;
    const int l15 = lane & 15, lk = lane >> 4;
    const int koh = blockIdx.y;
    const int by = blockIdx.x;
    const int n = by / 14, rb = (by % 14) * 4;

    const int wkol = (wv & 1) * 64;                // wave ko base (in block)
    const int wpx  = (wv >> 1) * 112;              // wave px base (local)
    const int wlane = (wv & 1) * 2048 + lk * 128 + l15 * 8;   // W ushort off

    int yl[7], xp[3][7];
#pragma unroll
    for (int nf = 0; nf < 7; ++nf) {
        int p = wpx + nf * 16 + l15;               // local pixel 0..223
        yl[nf] = p / 56;
        int x = p - yl[nf] * 56;
#pragma unroll
        for (int s = 0; s < 3; ++s) {
            int X = x + s;
            xp[s][nf] = ((X >> 4) << 10) + lk * 256 + ((X & 15) << 4);
        }
    }

    f32x4 acc[4][7];
#pragma unroll
    for (int m = 0; m < 4; ++m)
#pragma unroll
        for (int nf = 0; nf < 7; ++nf) acc[m][nf] = (f32x4)0.0f;

    bf16x8 wbuf[2][4];

// load W slice G_ (panel G_/3, s = G_%3) into wbuf[G_&1]
#define LOAD_WS(G_) do {                                                    \
    if constexpr ((G_) <= 35) {                                             \
        constexpr int p_ = (G_) / 3, sx_ = (G_) % 3;                        \
        const unsigned short* wp = Wt + ((size_t)(p_ * 2 + koh)) * 12288    \
                                   + sx_ * 4096 + wlane;                    \
        _Pragma("unroll")                                                   \
        for (int m = 0; m < 4; ++m)                                         \
            wbuf[(G_) & 1][m] = *(const bf16x8*)(wp + m * 512);             \
    } } while (0)

#define STAGE_ROW(C_, T_) do {                                              \
    gl2lds16(In + ((size_t)(((C_) * NBATCH + n) * PW + rb + (T_))) * 2048 + tid * 8, \
             &smem[((6 * (C_) + (T_)) % 12) * 2048 + tid * 8]);             \
} while (0)

#define STEP(PH, S_) do {                                                   \
    constexpr int g_ = (PH) * 3 + (S_);                                     \
    LOAD_WS(g_ + 1);                                                        \
    { const char* ib = (const char*)smem;                                   \
      bf16x8 b[7];                                                          \
      _Pragma("unroll")                                                     \
      for (int nf = 0; nf < 7; ++nf)                                        \
          b[nf] = *(const bf16x8*)(ib + roff[nf] + xp[(S_)][nf]);           \
      __builtin_amdgcn_s_setprio(1);                                        \
      _Pragma("unroll")                                                     \
      for (int m = 0; m < 4; ++m)                                           \
          _Pragma("unroll")                                                 \
          for (int nf = 0; nf < 7; ++nf)                                    \
              acc[m][nf] = __builtin_amdgcn_mfma_f32_16x16x32_bf16(         \
                  wbuf[g_ & 1][m], b[nf], acc[m][nf], 0, 0, 0);             \
      __builtin_amdgcn_s_setprio(0);                                        \
    }                                                                       \
} while (0)

    // prologue: input rows (0, t0..3), fence, W slice 0
    STAGE_ROW(0, 0); STAGE_ROW(0, 1); STAGE_ROW(0, 2); STAGE_ROW(0, 3);
    asm volatile("" ::: "memory");   // pin stage order vs W loads
    LOAD_WS(0);

#define PHASE(PH) do {                                                      \
    constexpr int cqp_ = (PH) / 3, rp_ = (PH) % 3;                          \
    constexpr int nI_ = (rp_ == 2) ? (cqp_ < 3 ? 2 : 0) : (cqp_ < 3 ? 2 : 1); \
    if constexpr (rp_ == 0) {                                               \
        STAGE_ROW(cqp_, 4);                                                 \
        if constexpr (cqp_ < 3) STAGE_ROW(cqp_ + 1, 0);                     \
    } else if constexpr (rp_ == 1) {                                        \
        STAGE_ROW(cqp_, 5);                                                 \
        if constexpr (cqp_ < 3) STAGE_ROW(cqp_ + 1, 1);                     \
    } else {                                                                \
        if constexpr (cqp_ < 3) { STAGE_ROW(cqp_ + 1, 2); STAGE_ROW(cqp_ + 1, 3); } \
    }                                                                       \
    asm volatile("s_waitcnt vmcnt(%0)" :: "i"(4 + nI_) : "memory");         \
    asm volatile("s_barrier" ::: "memory");                                 \
    { int roff[7];                                                          \
      _Pragma("unroll")                                                     \
      for (int nf = 0; nf < 7; ++nf) {                                      \
          int t = 6 * cqp_ + rp_ + yl[nf];                                  \
          roff[nf] = (t >= 12 ? t - 12 : t) << 12;                          \
      }                                                                     \
      STEP(PH, 0); STEP(PH, 1); STEP(PH, 2);                                \
    }                                                                       \
} while (0)

    PHASE(0);  PHASE(1);  PHASE(2);  PHASE(3);
    PHASE(4);  PHASE(5);  PHASE(6);  PHASE(7);
    PHASE(8);  PHASE(9);  PHASE(10); PHASE(11);

#undef PHASE
#undef STEP
#undef STAGE_ROW
#undef LOAD_WS

    // epilogue: D col = l15 (pixel), row = lk*4 + j (ko)
    const int sp0 = rb * 56 + wpx;
#pragma unroll
    for (int m = 0; m < 4; ++m) {
        int kb = koh * 128 + wkol + m * 16 + lk * 4;
        f32x4 bs = *(const f32x4*)(bias + kb);
#pragma unroll
        for (int nf = 0; nf < 7; ++nf) {
            float* ob = out + ((size_t)(n * K_OUT + kb) * IMG) + sp0 + nf * 16 + l15;
#pragma unroll
            for (int j = 0; j < 4; ++j)
                ob[(size_t)j * IMG] = acc[m][nf][j] + bs[j];
        }
    }
}

// ---- fallback (only if ws too small): naive fp32 direct conv ----
__global__ void conv_naive(const float* __restrict__ inp,
                           const float* __restrict__ ker,
                           const float* __restrict__ bias,
                           float* __restrict__ out, int total) {
    int o = blockIdx.x * blockDim.x + threadIdx.x;
    if (o >= total) return;
    int x = o % HW, y = (o / HW) % HW, ko = (o / IMG) % K_OUT, n = o / (IMG * K_OUT);
    float acc = bias[ko];
    for (int c = 0; c < C_IN; ++c)
        for (int r = 0; r < 3; ++r) {
            int iy = y + r - 1; if ((unsigned)iy >= HW) continue;
            for (int s = 0; s < 3; ++s) {
                int ix = x + s - 1; if ((unsigned)ix >= HW) continue;
                acc += inp[((n * C_IN + c) * HW + iy) * HW + ix]
                     * ker[((ko * C_IN + c) * 3 + r) * 3 + s];
            }
        }
    out[o] = acc;
}

extern "C" void kernel_launch(void* const* d_in, const int* in_sizes, int n_in,
                              void* d_out, int out_size, void* d_ws, size_t ws_size,
                              hipStream_t stream) {
    const float* inp  = (const float*)d_in[0];
    const float* ker  = (const float*)d_in[1];
    const float* bias = (const float*)d_in[2];
    float* out = (float*)d_out;

    const size_t need = (IN_WS_USHORT + WT_WS_USHORT) * 2;
    if (ws_size < need) {
        int total = NBATCH * K_OUT * IMG;
        conv_naive<<<(total + 255) / 256, 256, 0, stream>>>(inp, ker, bias, out, total);
        return;
    }

    unsigned short* inb = (unsigned short*)d_ws;
    unsigned short* wtb = inb + IN_WS_USHORT;

    prep_input<<<NBATCH * PW, 256, 0, stream>>>(inp, inb);
    prep_weights<<<144, 256, 0, stream>>>(ker, wtb);

    conv_mfma<<<dim3(448, 2), 256, 0, stream>>>(inb, wtb, bias, out);
}